// Round 4
// baseline (783.618 us; speedup 1.0000x reference)
//
#include <hip/hip_runtime.h>

typedef short short8  __attribute__((ext_vector_type(8)));
typedef float f32x4   __attribute__((ext_vector_type(4)));

#define B_TOTAL 4096
#define T_STEPS 512
#define F_IN    32
#define H_DIM   60
#define KW      92      // F + H
#define PITCH   72      // h-LDS row pitch in halves (16B-aligned, 2-way-free)

__device__ __forceinline__ unsigned short bf16hi(float f) {
    unsigned int u = __float_as_uint(f);
    u += 0x7FFFu + ((u >> 16) & 1u);          // round to nearest even
    return (unsigned short)(u >> 16);
}
__device__ __forceinline__ float bf16tof(unsigned short s) {
    return __uint_as_float(((unsigned int)s) << 16);
}
__device__ __forceinline__ float fast_sig(float z) {
    return 1.0f / (1.0f + __expf(-z));
}
__device__ __forceinline__ float fast_tanh(float z) {
    return 1.0f - 2.0f / (1.0f + __expf(2.0f * z));
}

__global__ __launch_bounds__(512, 2)
void lstm_mfma_kernel(const float* __restrict__ x,
                      const float* __restrict__ wk,
                      const float* __restrict__ bias,
                      const float* __restrict__ dense_w,
                      const float* __restrict__ dense_b,
                      float* __restrict__ out)
{
    // LDS: only h (bf16 hi + lo). Cols 0..59 = hidden units, 60..63 zero pad.
    __shared__ short Uhi[16][PITCH];
    __shared__ short Ulo[16][PITCH];

    const int tid  = threadIdx.x;
    const int lane = tid & 63;
    const int w    = tid >> 6;              // wave 0..7
    const int b0   = blockIdx.x * 16;
    const int lm   = lane & 15;             // M/N lane index
    const int kg   = lane >> 4;             // K octet group 0..3
    const int lk8  = kg * 8;

    // ---------------- B fragments (static weights), tiles n = 2w, 2w+1 ------
    // col c = 16n+lm = u*4+gate (gate order i,j,f,o); src layout [k][g*60+u].
    short8 bh[2][3], bl[2][3];
    float  biasv[2];
    #pragma unroll
    for (int tt = 0; tt < 2; ++tt) {
        const int n = w * 2 + tt;
        const int c = 16 * n + lm;
        const int u = c >> 2, g = c & 3;
        biasv[tt] = (c < 240) ? bias[g * 60 + u] : 0.0f;
        #pragma unroll
        for (int s = 0; s < 3; ++s) {
            short8 hv, lv;
            #pragma unroll
            for (int e = 0; e < 8; ++e) {
                const int k = s * 32 + lk8 + e;
                float wv = (k < KW && c < 240) ? wk[k * 240 + g * 60 + u] : 0.0f;
                unsigned short hh = bf16hi(wv);
                hv[e] = (short)hh;
                lv[e] = (short)bf16hi(wv - bf16tof(hh));
            }
            bh[tt][s] = hv;
            bl[tt][s] = lv;
        }
    }

    // ---------------- init h-LDS to zero (h0 = 0, pad = 0) ------------------
    for (int i = tid; i < 16 * PITCH; i += 512) {
        (&Uhi[0][0])[i] = 0;
        (&Ulo[0][0])[i] = 0;
    }

    // x source: lane owns row lm, k-columns lk8..lk8+7 (A s=0 fragment)
    const float* xrow = x + (size_t)(b0 + lm) * (T_STEPS * F_IN) + lk8;
    float4 xa = *reinterpret_cast<const float4*>(xrow);
    float4 xb = *reinterpret_cast<const float4*>(xrow + 4);

    float cst[2] = {0.f, 0.f};
    __syncthreads();

    // ---------------- T loop: 2 barriers / step -----------------------------
    for (int t = 0; t < T_STEPS; ++t) {
        // h fragments for K-steps s=1 (u 0..31) and s=2 (u 32..63)
        short8 ah1 = *reinterpret_cast<const short8*>(&Uhi[lm][lk8]);
        short8 ah2 = *reinterpret_cast<const short8*>(&Uhi[lm][32 + lk8]);
        short8 al1 = *reinterpret_cast<const short8*>(&Ulo[lm][lk8]);
        short8 al2 = *reinterpret_cast<const short8*>(&Ulo[lm][32 + lk8]);

        // convert current x to s=0 fragments (off critical path)
        float xv[8] = {xa.x, xa.y, xa.z, xa.w, xb.x, xb.y, xb.z, xb.w};
        short8 axh, axl;
        #pragma unroll
        for (int e = 0; e < 8; ++e) {
            unsigned short hh = bf16hi(xv[e]);
            axh[e] = (short)hh;
            axl[e] = (short)bf16hi(xv[e] - bf16tof(hh));
        }
        // prefetch x(t+1)
        const int tn = (t + 1 < T_STEPS) ? (t + 1) : t;
        float4 nxa = *reinterpret_cast<const float4*>(xrow + tn * F_IN);
        float4 nxb = *reinterpret_cast<const float4*>(xrow + tn * F_IN + 4);

        // gates = U @ W, bf16x2, 3 independent accumulator chains
        f32x4 gt[2];
        #pragma unroll
        for (int tt = 0; tt < 2; ++tt) {
            f32x4 a0 = {biasv[tt], biasv[tt], biasv[tt], biasv[tt]};
            f32x4 a1 = {0.f, 0.f, 0.f, 0.f};
            f32x4 a2 = {0.f, 0.f, 0.f, 0.f};
            a0 = __builtin_amdgcn_mfma_f32_16x16x32_bf16(axh, bh[tt][0], a0, 0, 0, 0);
            a1 = __builtin_amdgcn_mfma_f32_16x16x32_bf16(axl, bh[tt][0], a1, 0, 0, 0);
            a2 = __builtin_amdgcn_mfma_f32_16x16x32_bf16(axh, bl[tt][0], a2, 0, 0, 0);
            a0 = __builtin_amdgcn_mfma_f32_16x16x32_bf16(ah1, bh[tt][1], a0, 0, 0, 0);
            a1 = __builtin_amdgcn_mfma_f32_16x16x32_bf16(al1, bh[tt][1], a1, 0, 0, 0);
            a2 = __builtin_amdgcn_mfma_f32_16x16x32_bf16(ah1, bl[tt][1], a2, 0, 0, 0);
            a0 = __builtin_amdgcn_mfma_f32_16x16x32_bf16(ah2, bh[tt][2], a0, 0, 0, 0);
            a1 = __builtin_amdgcn_mfma_f32_16x16x32_bf16(al2, bh[tt][2], a1, 0, 0, 0);
            a2 = __builtin_amdgcn_mfma_f32_16x16x32_bf16(ah2, bl[tt][2], a2, 0, 0, 0);
            #pragma unroll
            for (int r = 0; r < 4; ++r) gt[tt][r] = a0[r] + (a1[r] + a2[r]);
        }

        __syncthreads();    // all waves done reading U(t)

        // nonlinearity, in-register via 4x4 quad butterfly transpose
        #pragma unroll
        for (int tt = 0; tt < 2; ++tt) {
            const int n = w * 2 + tt;
            if (n < 15) {
                float a0 = gt[tt][0], a1 = gt[tt][1], a2 = gt[tt][2], a3 = gt[tt][3];
                float s;
                // stage 1: xor 1, reg pairs (0,1) and (2,3)
                s = (lane & 1) ? a0 : a1;  s = __shfl_xor(s, 1);
                if (lane & 1) a0 = s; else a1 = s;
                s = (lane & 1) ? a2 : a3;  s = __shfl_xor(s, 1);
                if (lane & 1) a2 = s; else a3 = s;
                // stage 2: xor 2, reg pairs (0,2) and (1,3)
                s = (lane & 2) ? a0 : a2;  s = __shfl_xor(s, 2);
                if (lane & 2) a0 = s; else a2 = s;
                s = (lane & 2) ? a1 : a3;  s = __shfl_xor(s, 2);
                if (lane & 2) a1 = s; else a3 = s;
                // lane now holds i,j,f,o for (row = 4*kg + (lane&3),
                //                             u   = 4*n + ((lane>>2)&3))
                float ig = fast_sig(a0);
                float jg = fast_tanh(a1);
                float fg = fast_sig(a2 + 1.0f);     // forget bias
                float og = fast_sig(a3);
                cst[tt] = cst[tt] * fg + ig * jg;
                float h = fast_tanh(cst[tt]) * og;
                const int row = 4 * kg + (lane & 3);
                const int u   = 4 * n + ((lane >> 2) & 3);
                unsigned short hh = bf16hi(h);
                Uhi[row][u] = (short)hh;
                Ulo[row][u] = (short)bf16hi(h - bf16tof(hh));
            }
        }

        xa = nxa; xb = nxb;
        __syncthreads();    // U(t+1) ready
    }

    // ---------------- epilogue: out[b] = h . dense_w + dense_b --------------
    if (tid < 16) {
        float acc = dense_b[0];
        #pragma unroll 4
        for (int uu = 0; uu < H_DIM; ++uu) {
            float h = bf16tof((unsigned short)Uhi[tid][uu])
                    + bf16tof((unsigned short)Ulo[tid][uu]);
            acc = fmaf(h, dense_w[uu], acc);
        }
        out[b0 + tid] = acc;
    }
}

extern "C" void kernel_launch(void* const* d_in, const int* in_sizes, int n_in,
                              void* d_out, int out_size, void* d_ws, size_t ws_size,
                              hipStream_t stream) {
    const float* x       = (const float*)d_in[0];
    const float* wk      = (const float*)d_in[1];
    const float* bias    = (const float*)d_in[2];
    const float* dense_w = (const float*)d_in[3];
    const float* dense_b = (const float*)d_in[4];
    float* out = (float*)d_out;

    lstm_mfma_kernel<<<B_TOTAL / 16, 512, 0, stream>>>(
        x, wk, bias, dense_w, dense_b, out);
}

// Round 5
// 777.455 us; speedup vs baseline: 1.0079x; 1.0079x over previous
//
#include <hip/hip_runtime.h>

typedef short short8  __attribute__((ext_vector_type(8)));
typedef float f32x4   __attribute__((ext_vector_type(4)));

#define B_TOTAL 4096
#define T_STEPS 512
#define F_IN    32
#define H_DIM   60
#define KW      92      // F + H
#define BC      8       // batch rows per block (2 blocks/CU)
#define UPITCH  104     // U row pitch in halves (x: 0-31, h: 32-91, pad)
#define GPITCH  260     // gates row pitch in floats

__device__ __forceinline__ unsigned short bf16hi(float f) {
    unsigned int u = __float_as_uint(f);
    u += 0x7FFFu + ((u >> 16) & 1u);          // round to nearest even
    return (unsigned short)(u >> 16);
}
__device__ __forceinline__ float bf16tof(unsigned short s) {
    return __uint_as_float(((unsigned int)s) << 16);
}
__device__ __forceinline__ float fast_sig(float z) {
    return 1.0f / (1.0f + __expf(-z));
}
__device__ __forceinline__ float fast_tanh(float z) {
    return 1.0f - 2.0f / (1.0f + __expf(2.0f * z));
}

__global__ __launch_bounds__(256, 2)
void lstm_mfma_kernel(const float* __restrict__ x,
                      const float* __restrict__ wk,
                      const float* __restrict__ bias,
                      const float* __restrict__ dense_w,
                      const float* __restrict__ dense_b,
                      float* __restrict__ out)
{
    // U rows 0..7 = batch rows; rows 8..15 stay zero (M-pad for 16x16 MFMA).
    __shared__ short Uhi[16][UPITCH];
    __shared__ short Ulo[16][UPITCH];
    __shared__ float gates[BC][GPITCH];     // col c = u*4+gate

    const int tid  = threadIdx.x;
    const int lane = tid & 63;
    const int w    = tid >> 6;              // wave 0..3
    const int b0   = blockIdx.x * BC;
    const int lm   = lane & 15;             // A/B row-col lane index
    const int kg   = lane >> 4;             // K octet group 0..3
    const int lk8  = kg * 8;

    // ---------------- B fragments: wave w owns N-tiles n = 4w..4w+3 ---------
    // col c = 16n+lm = u*4+gate (i,j,f,o); src layout wk[k][g*60+u].
    // Forget-gate +1.0 bias folded into the accumulator init register.
    short8 bh[4][3], bl[4][3];
    f32x4  biasv[4];
    #pragma unroll
    for (int tt = 0; tt < 4; ++tt) {
        const int n = w * 4 + tt;
        const int c = 16 * n + lm;
        const int u = c >> 2, g = c & 3;
        float bv = (c < 240) ? (bias[g * 60 + u] + (g == 2 ? 1.0f : 0.0f)) : 0.0f;
        biasv[tt] = (f32x4){bv, bv, bv, bv};
        #pragma unroll
        for (int s = 0; s < 3; ++s) {
            short8 hv, lv;
            #pragma unroll
            for (int e = 0; e < 8; ++e) {
                const int k = s * 32 + lk8 + e;
                float wv = (k < KW && c < 240) ? wk[k * 240 + g * 60 + u] : 0.0f;
                unsigned short hh = bf16hi(wv);
                hv[e] = (short)hh;
                lv[e] = (short)bf16hi(wv - bf16tof(hh));
            }
            bh[tt][s] = hv;
            bl[tt][s] = lv;
        }
    }

    // ---------------- init U = 0 (h0 = 0, M-pad rows, K-pad cols) -----------
    for (int i = tid; i < 16 * UPITCH; i += 256) {
        (&Uhi[0][0])[i] = 0;
        (&Ulo[0][0])[i] = 0;
    }

    // x staging lanes: lane<16 of each wave; (row, quad) covered exactly once
    const bool xl = (lane < 16);
    const int  xr = 2 * w + (lane >> 3);    // batch row 0..7
    const int  xq = lane & 7;               // float4 quad 0..7
    const float* xptr = x + (size_t)(b0 + xr) * (T_STEPS * F_IN) + xq * 4;

    __syncthreads();                        // zero-init visible

    if (xl) {
        float4 v = *reinterpret_cast<const float4*>(xptr);
        float vv[4] = {v.x, v.y, v.z, v.w};
        #pragma unroll
        for (int j = 0; j < 4; ++j) {
            unsigned short hh = bf16hi(vv[j]);
            Uhi[xr][xq * 4 + j] = (short)hh;
            Ulo[xr][xq * 4 + j] = (short)bf16hi(vv[j] - bf16tof(hh));
        }
    }

    float cst[2] = {0.f, 0.f};              // cell state rows {2w, 2w+1}
    const f32x4 z4 = {0.f, 0.f, 0.f, 0.f};
    __syncthreads();

    // ---------------- T loop: 2 barriers / step -----------------------------
    for (int t = 0; t < T_STEPS; ++t) {
        // A fragments (hi/lo) for K-steps s=0 (x), s=1,2 (h)
        short8 a_h[3], a_l[3];
        #pragma unroll
        for (int s = 0; s < 3; ++s) {
            a_h[s] = *reinterpret_cast<const short8*>(&Uhi[lm][s * 32 + lk8]);
            a_l[s] = *reinterpret_cast<const short8*>(&Ulo[lm][s * 32 + lk8]);
        }

        // prefetch x(t+1) (hides under MFMA + barrier)
        float4 vx;
        if (xl) {
            const int tn = (t + 1 < T_STEPS) ? (t + 1) : t;
            vx = *reinterpret_cast<const float4*>(xptr + tn * F_IN);
        }

        // gates = U @ W, bf16x2: hi-chain (3 deep) + merged lo-chain (6 deep)
        f32x4 gt[4];
        __builtin_amdgcn_s_setprio(1);
        #pragma unroll
        for (int tt = 0; tt < 4; ++tt) {
            f32x4 a0 = __builtin_amdgcn_mfma_f32_16x16x32_bf16(a_h[0], bh[tt][0], biasv[tt], 0, 0, 0);
            f32x4 al = __builtin_amdgcn_mfma_f32_16x16x32_bf16(a_l[0], bh[tt][0], z4, 0, 0, 0);
            a0 = __builtin_amdgcn_mfma_f32_16x16x32_bf16(a_h[1], bh[tt][1], a0, 0, 0, 0);
            al = __builtin_amdgcn_mfma_f32_16x16x32_bf16(a_h[0], bl[tt][0], al, 0, 0, 0);
            a0 = __builtin_amdgcn_mfma_f32_16x16x32_bf16(a_h[2], bh[tt][2], a0, 0, 0, 0);
            al = __builtin_amdgcn_mfma_f32_16x16x32_bf16(a_l[1], bh[tt][1], al, 0, 0, 0);
            al = __builtin_amdgcn_mfma_f32_16x16x32_bf16(a_h[1], bl[tt][1], al, 0, 0, 0);
            al = __builtin_amdgcn_mfma_f32_16x16x32_bf16(a_l[2], bh[tt][2], al, 0, 0, 0);
            al = __builtin_amdgcn_mfma_f32_16x16x32_bf16(a_h[2], bl[tt][2], al, 0, 0, 0);
            #pragma unroll
            for (int r = 0; r < 4; ++r) gt[tt][r] = a0[r] + al[r];
        }
        __builtin_amdgcn_s_setprio(0);

        // gate write: only kg<2 rows are real (M=8)
        if (kg < 2) {
            #pragma unroll
            for (int tt = 0; tt < 4; ++tt) {
                const int c = 16 * (w * 4 + tt) + lm;
                if (c < 240) {
                    #pragma unroll
                    for (int r = 0; r < 4; ++r)
                        gates[kg * 4 + r][c] = gt[tt][r];
                }
            }
        }
        __syncthreads();                    // gates visible; U reads done

        // nonlinearity: wave w rows {2w, 2w+1}, u = lane
        if (lane < H_DIM) {
            #pragma unroll
            for (int r = 0; r < 2; ++r) {
                const int row = 2 * w + r;
                float4 gv = *reinterpret_cast<const float4*>(&gates[row][lane * 4]);
                float ig = fast_sig(gv.x);
                float jg = fast_tanh(gv.y);
                float fg = fast_sig(gv.z);          // +1 folded into bias
                float og = fast_sig(gv.w);
                cst[r] = cst[r] * fg + ig * jg;
                float h = fast_tanh(cst[r]) * og;
                unsigned short hh = bf16hi(h);
                Uhi[row][32 + lane] = (short)hh;
                Ulo[row][32 + lane] = (short)bf16hi(h - bf16tof(hh));
            }
        }
        // write x(t+1)
        if (xl) {
            float vv[4] = {vx.x, vx.y, vx.z, vx.w};
            #pragma unroll
            for (int j = 0; j < 4; ++j) {
                unsigned short hh = bf16hi(vv[j]);
                Uhi[xr][xq * 4 + j] = (short)hh;
                Ulo[xr][xq * 4 + j] = (short)bf16hi(vv[j] - bf16tof(hh));
            }
        }
        __syncthreads();                    // U(t+1) ready
    }

    // ---------------- epilogue: out[b] = h . dense_w + dense_b --------------
    if (tid < BC) {
        float acc = dense_b[0];
        #pragma unroll 4
        for (int uu = 0; uu < H_DIM; ++uu) {
            float h = bf16tof((unsigned short)Uhi[tid][32 + uu])
                    + bf16tof((unsigned short)Ulo[tid][32 + uu]);
            acc = fmaf(h, dense_w[uu], acc);
        }
        out[b0 + tid] = acc;
    }
}

extern "C" void kernel_launch(void* const* d_in, const int* in_sizes, int n_in,
                              void* d_out, int out_size, void* d_ws, size_t ws_size,
                              hipStream_t stream) {
    const float* x       = (const float*)d_in[0];
    const float* wk      = (const float*)d_in[1];
    const float* bias    = (const float*)d_in[2];
    const float* dense_w = (const float*)d_in[3];
    const float* dense_b = (const float*)d_in[4];
    float* out = (float*)d_out;

    lstm_mfma_kernel<<<B_TOTAL / BC, 256, 0, stream>>>(
        x, wk, bias, dense_w, dense_b, out);
}

// Round 6
// 618.435 us; speedup vs baseline: 1.2671x; 1.2571x over previous
//
#include <hip/hip_runtime.h>

typedef short short8  __attribute__((ext_vector_type(8)));
typedef float f32x4   __attribute__((ext_vector_type(4)));

#define B_TOTAL 4096
#define T_STEPS 512
#define F_IN    32
#define H_DIM   60
#define KW      92      // F + H
#define BC      16      // batch rows per block
#define UPITCH  104     // U row pitch in halves (x: 0-31, h: 32-91, pad->104)

__device__ __forceinline__ unsigned short bf16hi(float f) {
    unsigned int u = __float_as_uint(f);
    u += 0x7FFFu + ((u >> 16) & 1u);          // round to nearest even
    return (unsigned short)(u >> 16);
}
__device__ __forceinline__ float bf16tof(unsigned short s) {
    return __uint_as_float(((unsigned int)s) << 16);
}
__device__ __forceinline__ float fast_sig(float z) {
    return 1.0f / (1.0f + __expf(-z));
}
__device__ __forceinline__ float fast_tanh(float z) {
    return 1.0f - 2.0f / (1.0f + __expf(2.0f * z));
}

__global__ __launch_bounds__(512, 2)
void lstm_mfma_kernel(const float* __restrict__ x,
                      const float* __restrict__ wk,
                      const float* __restrict__ bias,
                      const float* __restrict__ dense_w,
                      const float* __restrict__ dense_b,
                      float* __restrict__ out)
{
    // Double-buffered U = [x_t | h_t] in bf16 hi/lo. Rows = 16 batch rows.
    __shared__ short Uhi[2][BC][UPITCH];
    __shared__ short Ulo[2][BC][UPITCH];

    const int tid  = threadIdx.x;
    const int lane = tid & 63;
    const int w    = tid >> 6;              // wave 0..7
    const int b0   = blockIdx.x * BC;
    const int lm   = lane & 15;
    const int kg   = lane >> 4;             // K octet group 0..3
    const int lk8  = kg * 8;

    // ---------------- A fragments = W^T (static). Wave w: M-tiles 2w, 2w+1 --
    // M-dim c = u*4 + gate (i,j,f,o interleave); src layout wk[k][g*60+u].
    // D-layout => lane (lm,kg) accumulator regs r=0..3 hold gates i,j,f,o of
    // unit u = 4*mt + kg for batch row b = lm.  Bias (+1 forget) folded in.
    short8 wh[2][3], wl[2][3];
    f32x4  biasv[2];
    #pragma unroll
    for (int tt = 0; tt < 2; ++tt) {
        const int mt = 2 * w + tt;
        if (mt < 15) {
            const int uo = 4 * mt + kg;          // unit this lane outputs
            f32x4 bv;
            #pragma unroll
            for (int r = 0; r < 4; ++r)
                bv[r] = bias[r * 60 + uo] + (r == 2 ? 1.0f : 0.0f);
            biasv[tt] = bv;
            const int c = 16 * mt + lm;          // A-operand M-row
            const int u = c >> 2, g = c & 3;
            #pragma unroll
            for (int s = 0; s < 3; ++s) {
                short8 hv, lv;
                #pragma unroll
                for (int e = 0; e < 8; ++e) {
                    const int k = s * 32 + lk8 + e;
                    float wv = (k < KW) ? wk[k * 240 + g * 60 + u] : 0.0f;
                    unsigned short hh = bf16hi(wv);
                    hv[e] = (short)hh;
                    lv[e] = (short)bf16hi(wv - bf16tof(hh));
                }
                wh[tt][s] = hv;
                wl[tt][s] = lv;
            }
        }
    }

    // ---------------- zero both buffers (h0 = 0, K-pad = 0) -----------------
    for (int i = tid; i < 2 * BC * UPITCH; i += 512) {
        (&Uhi[0][0][0])[i] = 0;
        (&Ulo[0][0][0])[i] = 0;
    }
    __syncthreads();

    // ---------------- stage x(0) into buffer 0 ------------------------------
    const bool xl = (tid < 128);
    const int  xr = tid >> 3;               // batch row 0..15
    const int  xq = tid & 7;                // float4 quad 0..7
    const float* xptr = x + (size_t)(b0 + xr) * (T_STEPS * F_IN) + xq * 4;
    if (xl) {
        float4 v = *reinterpret_cast<const float4*>(xptr);
        float vv[4] = {v.x, v.y, v.z, v.w};
        #pragma unroll
        for (int j = 0; j < 4; ++j) {
            unsigned short hh = bf16hi(vv[j]);
            Uhi[0][xr][xq * 4 + j] = (short)hh;
            Ulo[0][xr][xq * 4 + j] = (short)bf16hi(vv[j] - bf16tof(hh));
        }
    }

    float cst[2] = {0.f, 0.f};              // cell state for (b=lm, u=4mt+kg)
    const f32x4 z4 = {0.f, 0.f, 0.f, 0.f};
    int cur = 0;
    __syncthreads();

    // ---------------- T loop: ONE barrier per step --------------------------
    for (int t = 0; t < T_STEPS; ++t) {
        // B fragments (U data) from buf[cur]
        short8 uh[3], ul[3];
        #pragma unroll
        for (int s = 0; s < 3; ++s) {
            uh[s] = *reinterpret_cast<const short8*>(&Uhi[cur][lm][s * 32 + lk8]);
            ul[s] = *reinterpret_cast<const short8*>(&Ulo[cur][lm][s * 32 + lk8]);
        }

        // prefetch x(t+1)
        float4 vx;
        if (xl) {
            const int tn = (t + 1 < T_STEPS) ? (t + 1) : t;
            vx = *reinterpret_cast<const float4*>(xptr + tn * F_IN);
        }

        // gates^T = W^T @ U^T, bf16x2 (hi chain 3-deep + lo chain 6-deep)
        f32x4 gt[2];
        __builtin_amdgcn_s_setprio(1);
        #pragma unroll
        for (int tt = 0; tt < 2; ++tt) {
            if (2 * w + tt < 15) {
                f32x4 a0 = __builtin_amdgcn_mfma_f32_16x16x32_bf16(wh[tt][0], uh[0], biasv[tt], 0, 0, 0);
                f32x4 al = __builtin_amdgcn_mfma_f32_16x16x32_bf16(wh[tt][0], ul[0], z4, 0, 0, 0);
                al = __builtin_amdgcn_mfma_f32_16x16x32_bf16(wl[tt][0], uh[0], al, 0, 0, 0);
                a0 = __builtin_amdgcn_mfma_f32_16x16x32_bf16(wh[tt][1], uh[1], a0, 0, 0, 0);
                al = __builtin_amdgcn_mfma_f32_16x16x32_bf16(wh[tt][1], ul[1], al, 0, 0, 0);
                al = __builtin_amdgcn_mfma_f32_16x16x32_bf16(wl[tt][1], uh[1], al, 0, 0, 0);
                a0 = __builtin_amdgcn_mfma_f32_16x16x32_bf16(wh[tt][2], uh[2], a0, 0, 0, 0);
                al = __builtin_amdgcn_mfma_f32_16x16x32_bf16(wh[tt][2], ul[2], al, 0, 0, 0);
                al = __builtin_amdgcn_mfma_f32_16x16x32_bf16(wl[tt][2], uh[2], al, 0, 0, 0);
                #pragma unroll
                for (int r = 0; r < 4; ++r) gt[tt][r] = a0[r] + al[r];
            }
        }
        __builtin_amdgcn_s_setprio(0);

        const int nxt = cur ^ 1;

        // nonlinearity directly on accumulator registers; h -> buf[nxt]
        #pragma unroll
        for (int tt = 0; tt < 2; ++tt) {
            const int mt = 2 * w + tt;
            if (mt < 15) {
                float ig = fast_sig(gt[tt][0]);
                float jg = fast_tanh(gt[tt][1]);
                float fg = fast_sig(gt[tt][2]);      // +1 folded into bias
                float og = fast_sig(gt[tt][3]);
                cst[tt] = cst[tt] * fg + ig * jg;
                float h = fast_tanh(cst[tt]) * og;
                const int u = 4 * mt + kg;
                unsigned short hh = bf16hi(h);
                Uhi[nxt][lm][32 + u] = (short)hh;
                Ulo[nxt][lm][32 + u] = (short)bf16hi(h - bf16tof(hh));
            }
        }
        // x(t+1) -> buf[nxt]
        if (xl) {
            float vv[4] = {vx.x, vx.y, vx.z, vx.w};
            #pragma unroll
            for (int j = 0; j < 4; ++j) {
                unsigned short hh = bf16hi(vv[j]);
                Uhi[nxt][xr][xq * 4 + j] = (short)hh;
                Ulo[nxt][xr][xq * 4 + j] = (short)bf16hi(vv[j] - bf16tof(hh));
            }
        }
        __syncthreads();                    // h(t+1), x(t+1) visible
        cur = nxt;
    }

    // ---------------- epilogue: out[b] = h . dense_w + dense_b --------------
    if (tid < BC) {
        float acc = dense_b[0];
        #pragma unroll 4
        for (int uu = 0; uu < H_DIM; ++uu) {
            float h = bf16tof((unsigned short)Uhi[cur][tid][32 + uu])
                    + bf16tof((unsigned short)Ulo[cur][tid][32 + uu]);
            acc = fmaf(h, dense_w[uu], acc);
        }
        out[b0 + tid] = acc;
    }
}

extern "C" void kernel_launch(void* const* d_in, const int* in_sizes, int n_in,
                              void* d_out, int out_size, void* d_ws, size_t ws_size,
                              hipStream_t stream) {
    const float* x       = (const float*)d_in[0];
    const float* wk      = (const float*)d_in[1];
    const float* bias    = (const float*)d_in[2];
    const float* dense_w = (const float*)d_in[3];
    const float* dense_b = (const float*)d_in[4];
    float* out = (float*)d_out;

    lstm_mfma_kernel<<<B_TOTAL / BC, 512, 0, stream>>>(
        x, wk, bias, dense_w, dense_b, out);
}

// Round 7
// 605.644 us; speedup vs baseline: 1.2939x; 1.0211x over previous
//
#include <hip/hip_runtime.h>

typedef short short8  __attribute__((ext_vector_type(8)));
typedef float f32x4   __attribute__((ext_vector_type(4)));

#define B_TOTAL 4096
#define T_STEPS 512
#define F_IN    32
#define H_DIM   60
#define KW      92      // F + H
#define BC      16      // batch rows per block
#define UPITCH  104     // U row pitch in halves (x: 0-31, h: 32-91, pad->104)

__device__ __forceinline__ unsigned short bf16hi(float f) {
    unsigned int u = __float_as_uint(f);
    u += 0x7FFFu + ((u >> 16) & 1u);          // round to nearest even
    return (unsigned short)(u >> 16);
}
__device__ __forceinline__ unsigned short bf16trunc(float f) {
    return (unsigned short)(__float_as_uint(f) >> 16);   // truncate (for lo)
}
__device__ __forceinline__ float bf16tof(unsigned short s) {
    return __uint_as_float(((unsigned int)s) << 16);
}
__device__ __forceinline__ float fast_sig(float z) {
    return 1.0f / (1.0f + __expf(-z));
}
__device__ __forceinline__ float fast_tanh(float z) {
    return 1.0f - 2.0f / (1.0f + __expf(2.0f * z));
}

__global__ __launch_bounds__(512, 2)
void lstm_mfma_kernel(const float* __restrict__ x,
                      const float* __restrict__ wk,
                      const float* __restrict__ bias,
                      const float* __restrict__ dense_w,
                      const float* __restrict__ dense_b,
                      float* __restrict__ out)
{
    // Double-buffered U = [x_t | h_t] in bf16 hi/lo. Rows = 16 batch rows.
    __shared__ short Uhi[2][BC][UPITCH];
    __shared__ short Ulo[2][BC][UPITCH];

    const int tid  = threadIdx.x;
    const int lane = tid & 63;
    const int w    = tid >> 6;              // wave 0..7
    const int b0   = blockIdx.x * BC;
    const int lm   = lane & 15;
    const int kg   = lane >> 4;             // K octet group 0..3
    const int lk8  = kg * 8;

    // ---------------- A fragments = W^T (static). Wave w: M-tiles 2w, 2w+1 --
    // D-layout: lane (lm,kg) accumulator regs r=0..3 hold gates i,j,f,o of
    // unit u = 4*mt + kg for batch row b = lm. Bias (+1 forget) folded in.
    short8 wh[2][3], wl[2][3];
    f32x4  biasv[2];
    #pragma unroll
    for (int tt = 0; tt < 2; ++tt) {
        const int mt = 2 * w + tt;
        if (mt < 15) {
            const int uo = 4 * mt + kg;
            f32x4 bv;
            #pragma unroll
            for (int r = 0; r < 4; ++r)
                bv[r] = bias[r * 60 + uo] + (r == 2 ? 1.0f : 0.0f);
            biasv[tt] = bv;
            const int c = 16 * mt + lm;          // A-operand M-row
            const int u = c >> 2, g = c & 3;
            #pragma unroll
            for (int s = 0; s < 3; ++s) {
                short8 hv, lv;
                #pragma unroll
                for (int e = 0; e < 8; ++e) {
                    const int k = s * 32 + lk8 + e;
                    float wv = (k < KW) ? wk[k * 240 + g * 60 + u] : 0.0f;
                    unsigned short hh = bf16hi(wv);
                    hv[e] = (short)hh;
                    lv[e] = (short)bf16hi(wv - bf16tof(hh));
                }
                wh[tt][s] = hv;
                wl[tt][s] = lv;
            }
        }
    }

    // ---------------- zero both buffers (h0 = 0, K-pad = 0) -----------------
    for (int i = tid; i < 2 * BC * UPITCH; i += 512) {
        (&Uhi[0][0][0])[i] = 0;
        (&Ulo[0][0][0])[i] = 0;
    }
    __syncthreads();

    // ---------------- x staging: lane<16 of EVERY wave (balanced) -----------
    const bool xl = (lane < 16);
    const int  xr = (w << 1) | (lane >> 3);  // batch row 0..15
    const int  xq = lane & 7;                // float4 quad 0..7
    const float* xptr = x + (size_t)(b0 + xr) * (T_STEPS * F_IN) + xq * 4;

    if (xl) {
        float4 v = *reinterpret_cast<const float4*>(xptr);
        float vv[4] = {v.x, v.y, v.z, v.w};
        unsigned short h0 = bf16hi(vv[0]), h1 = bf16hi(vv[1]);
        unsigned short h2 = bf16hi(vv[2]), h3 = bf16hi(vv[3]);
        *reinterpret_cast<int*>(&Uhi[0][xr][xq * 4])     = (int)(h0 | ((unsigned)h1 << 16));
        *reinterpret_cast<int*>(&Uhi[0][xr][xq * 4 + 2]) = (int)(h2 | ((unsigned)h3 << 16));
        unsigned short l0 = bf16trunc(vv[0] - bf16tof(h0)), l1 = bf16trunc(vv[1] - bf16tof(h1));
        unsigned short l2 = bf16trunc(vv[2] - bf16tof(h2)), l3 = bf16trunc(vv[3] - bf16tof(h3));
        *reinterpret_cast<int*>(&Ulo[0][xr][xq * 4])     = (int)(l0 | ((unsigned)l1 << 16));
        *reinterpret_cast<int*>(&Ulo[0][xr][xq * 4 + 2]) = (int)(l2 | ((unsigned)l3 << 16));
    }

    float cst0 = 0.f, cst1 = 0.f;           // cell state for (b=lm, u=4mt+kg)
    const f32x4 z4 = {0.f, 0.f, 0.f, 0.f};
    const int mt0 = 2 * w, mt1 = 2 * w + 1;
    const bool t1ok = (mt1 < 15);
    int cur = 0;
    __syncthreads();

    // ---------------- T loop: ONE barrier per step --------------------------
    for (int t = 0; t < T_STEPS; ++t) {
        // B fragments (U data) from buf[cur]
        short8 uh0 = *reinterpret_cast<const short8*>(&Uhi[cur][lm][lk8]);
        short8 uh1 = *reinterpret_cast<const short8*>(&Uhi[cur][lm][32 + lk8]);
        short8 uh2 = *reinterpret_cast<const short8*>(&Uhi[cur][lm][64 + lk8]);
        short8 ul0 = *reinterpret_cast<const short8*>(&Ulo[cur][lm][lk8]);
        short8 ul1 = *reinterpret_cast<const short8*>(&Ulo[cur][lm][32 + lk8]);
        short8 ul2 = *reinterpret_cast<const short8*>(&Ulo[cur][lm][64 + lk8]);

        // prefetch x(t+1)
        float4 vx;
        if (xl) {
            const int tn = (t + 1 < T_STEPS) ? (t + 1) : t;
            vx = *reinterpret_cast<const float4*>(xptr + tn * F_IN);
        }

        const int nxt = cur ^ 1;

        // ---- tile 0: 3 parallel chains of depth 3 ----
        __builtin_amdgcn_s_setprio(1);
        f32x4 p0 = __builtin_amdgcn_mfma_f32_16x16x32_bf16(wh[0][0], uh0, biasv[0], 0, 0, 0);
        f32x4 p1 = __builtin_amdgcn_mfma_f32_16x16x32_bf16(wl[0][0], uh0, z4, 0, 0, 0);
        f32x4 p2 = __builtin_amdgcn_mfma_f32_16x16x32_bf16(wh[0][0], ul0, z4, 0, 0, 0);
        p0 = __builtin_amdgcn_mfma_f32_16x16x32_bf16(wh[0][1], uh1, p0, 0, 0, 0);
        p1 = __builtin_amdgcn_mfma_f32_16x16x32_bf16(wl[0][1], uh1, p1, 0, 0, 0);
        p2 = __builtin_amdgcn_mfma_f32_16x16x32_bf16(wh[0][1], ul1, p2, 0, 0, 0);
        p0 = __builtin_amdgcn_mfma_f32_16x16x32_bf16(wh[0][2], uh2, p0, 0, 0, 0);
        p1 = __builtin_amdgcn_mfma_f32_16x16x32_bf16(wl[0][2], uh2, p1, 0, 0, 0);
        p2 = __builtin_amdgcn_mfma_f32_16x16x32_bf16(wh[0][2], ul2, p2, 0, 0, 0);

        // ---- tile 1: issue chains (independent; overlaps tile-0 nonlin) ----
        f32x4 q0, q1, q2;
        if (t1ok) {
            q0 = __builtin_amdgcn_mfma_f32_16x16x32_bf16(wh[1][0], uh0, biasv[1], 0, 0, 0);
            q1 = __builtin_amdgcn_mfma_f32_16x16x32_bf16(wl[1][0], uh0, z4, 0, 0, 0);
            q2 = __builtin_amdgcn_mfma_f32_16x16x32_bf16(wh[1][0], ul0, z4, 0, 0, 0);
            q0 = __builtin_amdgcn_mfma_f32_16x16x32_bf16(wh[1][1], uh1, q0, 0, 0, 0);
            q1 = __builtin_amdgcn_mfma_f32_16x16x32_bf16(wl[1][1], uh1, q1, 0, 0, 0);
            q2 = __builtin_amdgcn_mfma_f32_16x16x32_bf16(wh[1][1], ul1, q2, 0, 0, 0);
            q0 = __builtin_amdgcn_mfma_f32_16x16x32_bf16(wh[1][2], uh2, q0, 0, 0, 0);
            q1 = __builtin_amdgcn_mfma_f32_16x16x32_bf16(wl[1][2], uh2, q1, 0, 0, 0);
            q2 = __builtin_amdgcn_mfma_f32_16x16x32_bf16(wh[1][2], ul2, q2, 0, 0, 0);
        }
        __builtin_amdgcn_s_setprio(0);

        // ---- tile 0 nonlinearity + h write (overlaps tile-1 MFMA drain) ----
        {
            float gi = p0[0] + p1[0] + p2[0];
            float gj = p0[1] + p1[1] + p2[1];
            float gf = p0[2] + p1[2] + p2[2];
            float go = p0[3] + p1[3] + p2[3];
            float ig = fast_sig(gi);
            float jg = fast_tanh(gj);
            float fg = fast_sig(gf);            // +1 folded into bias
            float og = fast_sig(go);
            cst0 = cst0 * fg + ig * jg;
            float h = fast_tanh(cst0) * og;
            const int u = 4 * mt0 + kg;
            unsigned short hh = bf16hi(h);
            Uhi[nxt][lm][32 + u] = (short)hh;
            Ulo[nxt][lm][32 + u] = (short)bf16trunc(h - bf16tof(hh));
        }

        // ---- tile 1 nonlinearity + h write ----
        if (t1ok) {
            float gi = q0[0] + q1[0] + q2[0];
            float gj = q0[1] + q1[1] + q2[1];
            float gf = q0[2] + q1[2] + q2[2];
            float go = q0[3] + q1[3] + q2[3];
            float ig = fast_sig(gi);
            float jg = fast_tanh(gj);
            float fg = fast_sig(gf);
            float og = fast_sig(go);
            cst1 = cst1 * fg + ig * jg;
            float h = fast_tanh(cst1) * og;
            const int u = 4 * mt1 + kg;
            unsigned short hh = bf16hi(h);
            Uhi[nxt][lm][32 + u] = (short)hh;
            Ulo[nxt][lm][32 + u] = (short)bf16trunc(h - bf16tof(hh));
        }

        // ---- x(t+1) -> buf[nxt], packed b32 writes ----
        if (xl) {
            float vv[4] = {vx.x, vx.y, vx.z, vx.w};
            unsigned short h0 = bf16hi(vv[0]), h1 = bf16hi(vv[1]);
            unsigned short h2 = bf16hi(vv[2]), h3 = bf16hi(vv[3]);
            *reinterpret_cast<int*>(&Uhi[nxt][xr][xq * 4])     = (int)(h0 | ((unsigned)h1 << 16));
            *reinterpret_cast<int*>(&Uhi[nxt][xr][xq * 4 + 2]) = (int)(h2 | ((unsigned)h3 << 16));
            unsigned short l0 = bf16trunc(vv[0] - bf16tof(h0)), l1 = bf16trunc(vv[1] - bf16tof(h1));
            unsigned short l2 = bf16trunc(vv[2] - bf16tof(h2)), l3 = bf16trunc(vv[3] - bf16tof(h3));
            *reinterpret_cast<int*>(&Ulo[nxt][xr][xq * 4])     = (int)(l0 | ((unsigned)l1 << 16));
            *reinterpret_cast<int*>(&Ulo[nxt][xr][xq * 4 + 2]) = (int)(l2 | ((unsigned)l3 << 16));
        }
        __syncthreads();                    // h(t+1), x(t+1) visible
        cur = nxt;
    }

    // ---------------- epilogue: out[b] = h . dense_w + dense_b --------------
    if (tid < BC) {
        float acc = dense_b[0];
        #pragma unroll 4
        for (int uu = 0; uu < H_DIM; ++uu) {
            float h = bf16tof((unsigned short)Uhi[cur][tid][32 + uu])
                    + bf16tof((unsigned short)Ulo[cur][tid][32 + uu]);
            acc = fmaf(h, dense_w[uu], acc);
        }
        out[b0 + tid] = acc;
    }
}

extern "C" void kernel_launch(void* const* d_in, const int* in_sizes, int n_in,
                              void* d_out, int out_size, void* d_ws, size_t ws_size,
                              hipStream_t stream) {
    const float* x       = (const float*)d_in[0];
    const float* wk      = (const float*)d_in[1];
    const float* bias    = (const float*)d_in[2];
    const float* dense_w = (const float*)d_in[3];
    const float* dense_b = (const float*)d_in[4];
    float* out = (float*)d_out;

    lstm_mfma_kernel<<<B_TOTAL / BC, 512, 0, stream>>>(
        x, wk, bias, dense_w, dense_b, out);
}

// Round 8
// 374.752 us; speedup vs baseline: 2.0910x; 1.6161x over previous
//
#include <hip/hip_runtime.h>

typedef short short8  __attribute__((ext_vector_type(8)));
typedef float f32x4   __attribute__((ext_vector_type(4)));

#define B_TOTAL 4096
#define T_STEPS 512
#define F_IN    32
#define H_DIM   60
#define KW      92      // F + H
#define BC      16      // batch rows per block
#define UPITCH  104     // U row pitch in halves (x: 0-31, h: 32-91, pad->104)

#define MFMA(A, B, C) __builtin_amdgcn_mfma_f32_16x16x32_bf16((A), (B), (C), 0, 0, 0)

__device__ __forceinline__ unsigned short bf16rne(float f) {
    unsigned int u = __float_as_uint(f);
    u += 0x7FFFu + ((u >> 16) & 1u);
    return (unsigned short)(u >> 16);
}
__device__ __forceinline__ float bf16tof(unsigned short s) {
    return __uint_as_float(((unsigned int)s) << 16);
}
__device__ __forceinline__ float rcpf(float z) {
    return __builtin_amdgcn_rcpf(z);            // v_rcp_f32, 1 ulp
}
__device__ __forceinline__ float sigf(float z) {
    return rcpf(1.0f + __expf(-z));
}
__device__ __forceinline__ float tanhf_(float z) {
    return fmaf(-2.0f, rcpf(1.0f + __expf(2.0f * z)), 1.0f);
}

__global__ __launch_bounds__(512, 2)
void lstm_mfma_kernel(const float* __restrict__ x,
                      const float* __restrict__ wk,
                      const float* __restrict__ bias,
                      const float* __restrict__ dense_w,
                      const float* __restrict__ dense_b,
                      float* __restrict__ out)
{
    // Double-buffered U = [x_t | h_t] in bf16 hi/lo planes.
    __shared__ __align__(16) short Uhi[2][BC][UPITCH];
    __shared__ __align__(16) short Ulo[2][BC][UPITCH];

    const int tid  = threadIdx.x;
    const int lane = tid & 63;
    const int w    = tid >> 6;              // wave 0..7
    const int b0   = blockIdx.x * BC;
    const int lm   = lane & 15;
    const int kg   = lane >> 4;             // K octet group 0..3
    const int lk8  = kg * 8;

    // ---------------- A fragments = W^T (static). Wave w: M-tiles 2w, 2w+1 --
    // D-layout: lane (lm,kg) accumulator regs r=0..3 hold gates i,j,f,o of
    // unit u = 4*mt + kg for batch row b = lm. Bias (+1 forget) folded in.
    short8 wh[2][3], wl[2][3];
    f32x4  biasv[2];
    #pragma unroll
    for (int tt = 0; tt < 2; ++tt) {
        const int mt = 2 * w + tt;
        if (mt < 15) {
            const int uo = 4 * mt + kg;
            f32x4 bv;
            #pragma unroll
            for (int r = 0; r < 4; ++r)
                bv[r] = bias[r * 60 + uo] + (r == 2 ? 1.0f : 0.0f);
            biasv[tt] = bv;
            const int c = 16 * mt + lm;          // A-operand M-row
            const int u = c >> 2, g = c & 3;
            #pragma unroll
            for (int s = 0; s < 3; ++s) {
                short8 hv, lv;
                #pragma unroll
                for (int e = 0; e < 8; ++e) {
                    const int k = s * 32 + lk8 + e;
                    float wv = (k < KW) ? wk[k * 240 + g * 60 + u] : 0.0f;
                    unsigned short hh = bf16rne(wv);
                    hv[e] = (short)hh;
                    lv[e] = (short)bf16rne(wv - bf16tof(hh));
                }
                wh[tt][s] = hv;
                wl[tt][s] = lv;
            }
        } else {
            biasv[tt] = (f32x4){0.f, 0.f, 0.f, 0.f};
            #pragma unroll
            for (int s = 0; s < 3; ++s) { wh[tt][s] = (short8)0; wl[tt][s] = (short8)0; }
        }
    }

    // ---------------- zero both buffers (h0 = 0, K-pad = 0) -----------------
    for (int i = tid; i < 2 * BC * UPITCH; i += 512) {
        (&Uhi[0][0][0])[i] = 0;
        (&Ulo[0][0][0])[i] = 0;
    }
    __syncthreads();

    // ---------------- x staging: lane<16 of EVERY wave (balanced) -----------
    const bool xl = (lane < 16);
    const int  xr = (w << 1) | (lane >> 3);  // batch row 0..15
    const int  xq = lane & 7;                // float4 quad 0..7
    const float* xptr = x + (size_t)(b0 + xr) * (T_STEPS * F_IN) + xq * 4;

// pack float4 VEC into bf16 hi/lo planes of buffer BUF via truncation splits
#define XSTAGE(BUF, VEC)                                                        \
    {                                                                           \
        unsigned q0 = __float_as_uint((VEC).x), q1 = __float_as_uint((VEC).y);  \
        unsigned q2 = __float_as_uint((VEC).z), q3 = __float_as_uint((VEC).w);  \
        int2 hp;                                                                \
        hp.x = (int)__builtin_amdgcn_perm(q1, q0, 0x07060302u);                 \
        hp.y = (int)__builtin_amdgcn_perm(q3, q2, 0x07060302u);                 \
        *reinterpret_cast<int2*>(&Uhi[BUF][xr][xq * 4]) = hp;                   \
        float l0 = (VEC).x - __uint_as_float(q0 & 0xFFFF0000u);                 \
        float l1 = (VEC).y - __uint_as_float(q1 & 0xFFFF0000u);                 \
        float l2 = (VEC).z - __uint_as_float(q2 & 0xFFFF0000u);                 \
        float l3 = (VEC).w - __uint_as_float(q3 & 0xFFFF0000u);                 \
        int2 lp;                                                                \
        lp.x = (int)__builtin_amdgcn_perm(__float_as_uint(l1), __float_as_uint(l0), 0x07060302u); \
        lp.y = (int)__builtin_amdgcn_perm(__float_as_uint(l3), __float_as_uint(l2), 0x07060302u); \
        *reinterpret_cast<int2*>(&Ulo[BUF][xr][xq * 4]) = lp;                   \
    }

    if (xl) {
        float4 v0 = *reinterpret_cast<const float4*>(xptr);
        XSTAGE(0, v0)
    }

    float cst0 = 0.f, cst1 = 0.f;           // cell state for (b=lm, u=4mt+kg)
    const f32x4 z4 = {0.f, 0.f, 0.f, 0.f};
    const int mt0 = 2 * w, mt1 = 2 * w + 1;
    const bool t1ok = (mt1 < 15);
    __syncthreads();

// one LSTM step: read U[CUR], MFMA, nonlinearity, write U[NXT], barrier
#define STEP(CUR, NXT, TT)                                                      \
    {                                                                           \
        short8 uh0 = *reinterpret_cast<const short8*>(&Uhi[CUR][lm][lk8]);      \
        short8 uh1 = *reinterpret_cast<const short8*>(&Uhi[CUR][lm][32 + lk8]); \
        short8 uh2 = *reinterpret_cast<const short8*>(&Uhi[CUR][lm][64 + lk8]); \
        short8 ul0 = *reinterpret_cast<const short8*>(&Ulo[CUR][lm][lk8]);      \
        short8 ul1 = *reinterpret_cast<const short8*>(&Ulo[CUR][lm][32 + lk8]); \
        short8 ul2 = *reinterpret_cast<const short8*>(&Ulo[CUR][lm][64 + lk8]); \
        float4 vx;                                                              \
        if (xl) {                                                               \
            const int tn = ((TT) + 1 < T_STEPS) ? (TT) + 1 : (TT);              \
            vx = *reinterpret_cast<const float4*>(xptr + tn * F_IN);            \
        }                                                                       \
        __builtin_amdgcn_s_setprio(1);                                          \
        f32x4 p0 = MFMA(wh[0][0], uh0, biasv[0]);                               \
        f32x4 pl = MFMA(wl[0][0], uh0, z4);                                     \
        f32x4 q0 = MFMA(wh[1][0], uh0, biasv[1]);                               \
        f32x4 ql = MFMA(wl[1][0], uh0, z4);                                     \
        p0 = MFMA(wh[0][1], uh1, p0);                                           \
        pl = MFMA(wh[0][0], ul0, pl);                                           \
        q0 = MFMA(wh[1][1], uh1, q0);                                           \
        ql = MFMA(wh[1][0], ul0, ql);                                           \
        p0 = MFMA(wh[0][2], uh2, p0);                                           \
        pl = MFMA(wl[0][1], uh1, pl);                                           \
        q0 = MFMA(wh[1][2], uh2, q0);                                           \
        ql = MFMA(wl[1][1], uh1, ql);                                           \
        pl = MFMA(wh[0][1], ul1, pl);                                           \
        ql = MFMA(wh[1][1], ul1, ql);                                           \
        pl = MFMA(wl[0][2], uh2, pl);                                           \
        ql = MFMA(wl[1][2], uh2, ql);                                           \
        pl = MFMA(wh[0][2], ul2, pl);                                           \
        ql = MFMA(wh[1][2], ul2, ql);                                           \
        __builtin_amdgcn_s_setprio(0);                                          \
        {                                                                       \
            float gi = p0[0] + pl[0], gj = p0[1] + pl[1];                       \
            float gf = p0[2] + pl[2], go = p0[3] + pl[3];                       \
            float ig = sigf(gi), jg = tanhf_(gj);                               \
            float fg = sigf(gf), og = sigf(go);                                 \
            cst0 = cst0 * fg + ig * jg;                                         \
            float h = tanhf_(cst0) * og;                                        \
            const int u = 4 * mt0 + kg;                                         \
            unsigned uhb = __float_as_uint(h);                                  \
            Uhi[NXT][lm][32 + u] = (short)(uhb >> 16);                          \
            float hl = h - __uint_as_float(uhb & 0xFFFF0000u);                  \
            Ulo[NXT][lm][32 + u] = (short)(__float_as_uint(hl) >> 16);          \
        }                                                                       \
        if (t1ok) {                                                             \
            float gi = q0[0] + ql[0], gj = q0[1] + ql[1];                       \
            float gf = q0[2] + ql[2], go = q0[3] + ql[3];                       \
            float ig = sigf(gi), jg = tanhf_(gj);                               \
            float fg = sigf(gf), og = sigf(go);                                 \
            cst1 = cst1 * fg + ig * jg;                                         \
            float h = tanhf_(cst1) * og;                                        \
            const int u = 4 * mt1 + kg;                                         \
            unsigned uhb = __float_as_uint(h);                                  \
            Uhi[NXT][lm][32 + u] = (short)(uhb >> 16);                          \
            float hl = h - __uint_as_float(uhb & 0xFFFF0000u);                  \
            Ulo[NXT][lm][32 + u] = (short)(__float_as_uint(hl) >> 16);          \
        }                                                                       \
        if (xl) XSTAGE(NXT, vx)                                                 \
        __syncthreads();                                                        \
    }

    for (int t = 0; t < T_STEPS; t += 2) {
        STEP(0, 1, t)
        STEP(1, 0, t + 1)
    }

    // ---------------- epilogue: out[b] = h . dense_w + dense_b --------------
    // After an even number of steps the live buffer is 0.
    if (tid < BC) {
        float acc = dense_b[0];
        #pragma unroll 4
        for (int uu = 0; uu < H_DIM; ++uu) {
            float h = bf16tof((unsigned short)Uhi[0][tid][32 + uu])
                    + bf16tof((unsigned short)Ulo[0][tid][32 + uu]);
            acc = fmaf(h, dense_w[uu], acc);
        }
        out[b0 + tid] = acc;
    }
}

extern "C" void kernel_launch(void* const* d_in, const int* in_sizes, int n_in,
                              void* d_out, int out_size, void* d_ws, size_t ws_size,
                              hipStream_t stream) {
    const float* x       = (const float*)d_in[0];
    const float* wk      = (const float*)d_in[1];
    const float* bias    = (const float*)d_in[2];
    const float* dense_w = (const float*)d_in[3];
    const float* dense_b = (const float*)d_in[4];
    float* out = (float*)d_out;

    lstm_mfma_kernel<<<B_TOTAL / BC, 512, 0, stream>>>(
        x, wk, bias, dense_w, dense_b, out);
}

// Round 9
// 368.144 us; speedup vs baseline: 2.1286x; 1.0179x over previous
//
#include <hip/hip_runtime.h>

typedef short short8  __attribute__((ext_vector_type(8)));
typedef float f32x4   __attribute__((ext_vector_type(4)));

#define B_TOTAL 4096
#define T_STEPS 512
#define F_IN    32
#define H_DIM   60
#define KW      92      // F + H
#define BC      16      // batch rows per block
#define HPITCH  72      // h-LDS row pitch in halves (144B rows, 2-way-free)

#define MFMA(A, B, C) __builtin_amdgcn_mfma_f32_16x16x32_bf16((A), (B), (C), 0, 0, 0)

__device__ __forceinline__ unsigned short bf16rne(float f) {
    unsigned int u = __float_as_uint(f);
    u += 0x7FFFu + ((u >> 16) & 1u);
    return (unsigned short)(u >> 16);
}
__device__ __forceinline__ float bf16tof(unsigned short s) {
    return __uint_as_float(((unsigned int)s) << 16);
}
__device__ __forceinline__ float rcpf(float z) {
    return __builtin_amdgcn_rcpf(z);            // v_rcp_f32, 1 ulp
}
__device__ __forceinline__ float exp2f_(float z) {
#if __has_builtin(__builtin_amdgcn_exp2f)
    return __builtin_amdgcn_exp2f(z);           // v_exp_f32
#else
    float r; asm("v_exp_f32 %0, %1" : "=v"(r) : "v"(z)); return r;
#endif
}
// zs pre-scaled by log2e:
__device__ __forceinline__ float sig2(float zs) {      // sigmoid(z), zs=z*log2e
    return rcpf(1.0f + exp2f_(-zs));
}
// zs pre-scaled by 2*log2e:
__device__ __forceinline__ float tanh2(float zs) {     // tanh(z), zs=2z*log2e
    return fmaf(-2.0f, rcpf(1.0f + exp2f_(zs)), 1.0f);
}

// convert float4 pair -> bf16 hi/lo short8 fragments (truncation split)
#define CVT(VA, VB, OH, OL)                                                     \
    {                                                                           \
        unsigned c0 = __float_as_uint((VA).x), c1 = __float_as_uint((VA).y);    \
        unsigned c2 = __float_as_uint((VA).z), c3 = __float_as_uint((VA).w);    \
        unsigned c4 = __float_as_uint((VB).x), c5 = __float_as_uint((VB).y);    \
        unsigned c6 = __float_as_uint((VB).z), c7 = __float_as_uint((VB).w);    \
        int4 hp;                                                                \
        hp.x = (int)__builtin_amdgcn_perm(c1, c0, 0x07060302u);                 \
        hp.y = (int)__builtin_amdgcn_perm(c3, c2, 0x07060302u);                 \
        hp.z = (int)__builtin_amdgcn_perm(c5, c4, 0x07060302u);                 \
        hp.w = (int)__builtin_amdgcn_perm(c7, c6, 0x07060302u);                 \
        OH = __builtin_bit_cast(short8, hp);                                    \
        float l0 = (VA).x - __uint_as_float(c0 & 0xFFFF0000u);                  \
        float l1 = (VA).y - __uint_as_float(c1 & 0xFFFF0000u);                  \
        float l2 = (VA).z - __uint_as_float(c2 & 0xFFFF0000u);                  \
        float l3 = (VA).w - __uint_as_float(c3 & 0xFFFF0000u);                  \
        float l4 = (VB).x - __uint_as_float(c4 & 0xFFFF0000u);                  \
        float l5 = (VB).y - __uint_as_float(c5 & 0xFFFF0000u);                  \
        float l6 = (VB).z - __uint_as_float(c6 & 0xFFFF0000u);                  \
        float l7 = (VB).w - __uint_as_float(c7 & 0xFFFF0000u);                  \
        int4 lp;                                                                \
        lp.x = (int)__builtin_amdgcn_perm(__float_as_uint(l1), __float_as_uint(l0), 0x07060302u); \
        lp.y = (int)__builtin_amdgcn_perm(__float_as_uint(l3), __float_as_uint(l2), 0x07060302u); \
        lp.z = (int)__builtin_amdgcn_perm(__float_as_uint(l5), __float_as_uint(l4), 0x07060302u); \
        lp.w = (int)__builtin_amdgcn_perm(__float_as_uint(l7), __float_as_uint(l6), 0x07060302u); \
        OL = __builtin_bit_cast(short8, lp);                                    \
    }

__global__ __launch_bounds__(512, 2)
void lstm_mfma_kernel(const float* __restrict__ x,
                      const float* __restrict__ wk,
                      const float* __restrict__ bias,
                      const float* __restrict__ dense_w,
                      const float* __restrict__ dense_b,
                      float* __restrict__ out)
{
    // Double-buffered h-state only (x never touches LDS), bf16 hi/lo planes.
    __shared__ __align__(16) short Hhi[2][BC][HPITCH];
    __shared__ __align__(16) short Hlo[2][BC][HPITCH];

    const int tid  = threadIdx.x;
    const int lane = tid & 63;
    const int w    = tid >> 6;              // wave 0..7
    const int b0   = blockIdx.x * BC;
    const int lm   = lane & 15;
    const int kg   = lane >> 4;             // K octet group 0..3
    const int lk8  = kg * 8;

    const float LOG2E = 1.44269504088896340736f;

    // ---------------- A fragments = W^T (static), exp2-prescaled ------------
    // Wave w owns M-tiles 2w, 2w+1. D-layout: lane (lm,kg) acc regs r=0..3
    // hold gates i,j,f,o (pre-scaled) of unit u=4*mt+kg for batch row b=lm.
    // Gate j scaled by 2*log2e (consumed by tanh), others by log2e (sigmoid);
    // forget +1.0 bias folded before scaling.
    short8 wh[2][3], wl[2][3];
    f32x4  biasv[2];
    #pragma unroll
    for (int tt = 0; tt < 2; ++tt) {
        const int mt = 2 * w + tt;
        if (mt < 15) {
            const int uo = 4 * mt + kg;
            f32x4 bv;
            #pragma unroll
            for (int r = 0; r < 4; ++r) {
                const float sc = (r == 1) ? 2.0f * LOG2E : LOG2E;
                bv[r] = (bias[r * 60 + uo] + (r == 2 ? 1.0f : 0.0f)) * sc;
            }
            biasv[tt] = bv;
            const int c = 16 * mt + lm;          // A-operand M-row
            const int u = c >> 2, g = c & 3;
            const float gsc = (g == 1) ? 2.0f * LOG2E : LOG2E;
            #pragma unroll
            for (int s = 0; s < 3; ++s) {
                short8 hv, lv;
                #pragma unroll
                for (int e = 0; e < 8; ++e) {
                    const int k = s * 32 + lk8 + e;
                    float wv = (k < KW) ? wk[k * 240 + g * 60 + u] * gsc : 0.0f;
                    unsigned short hh = bf16rne(wv);
                    hv[e] = (short)hh;
                    lv[e] = (short)bf16rne(wv - bf16tof(hh));
                }
                wh[tt][s] = hv;
                wl[tt][s] = lv;
            }
        } else {
            biasv[tt] = (f32x4){0.f, 0.f, 0.f, 0.f};
            #pragma unroll
            for (int s = 0; s < 3; ++s) { wh[tt][s] = (short8)0; wl[tt][s] = (short8)0; }
        }
    }

    // ---------------- zero both h buffers (h0 = 0, pad cols 60..63 = 0) -----
    for (int i = tid; i < 2 * BC * HPITCH; i += 512) {
        (&Hhi[0][0][0])[i] = 0;
        (&Hlo[0][0][0])[i] = 0;
    }

    // ---------------- x fragment source: lane owns (row lm, k lk8..lk8+7) ---
    const float* xrow = x + (size_t)(b0 + lm) * (T_STEPS * F_IN) + lk8;
    float4 va0 = *reinterpret_cast<const float4*>(xrow);
    float4 vb0 = *reinterpret_cast<const float4*>(xrow + 4);
    short8 axh, axl;
    CVT(va0, vb0, axh, axl)

    float cst0 = 0.f, cst1 = 0.f;           // cell state for (b=lm, u=4mt+kg)
    const f32x4 z4 = {0.f, 0.f, 0.f, 0.f};
    const int mt0 = 2 * w, mt1 = 2 * w + 1;
    const bool t1ok = (mt1 < 15);
    __syncthreads();

// one LSTM step: x-frag from regs, h-frags from LDS[CUR], write h -> LDS[NXT]
#define STEP(CUR, NXT, TT)                                                      \
    {                                                                           \
        const int tn = ((TT) + 1 < T_STEPS) ? (TT) + 1 : (TT);                  \
        float4 nva = *reinterpret_cast<const float4*>(xrow + tn * F_IN);        \
        float4 nvb = *reinterpret_cast<const float4*>(xrow + tn * F_IN + 4);    \
        short8 uh1 = *reinterpret_cast<const short8*>(&Hhi[CUR][lm][lk8]);      \
        short8 uh2 = *reinterpret_cast<const short8*>(&Hhi[CUR][lm][32 + lk8]); \
        short8 ul1 = *reinterpret_cast<const short8*>(&Hlo[CUR][lm][lk8]);      \
        short8 ul2 = *reinterpret_cast<const short8*>(&Hlo[CUR][lm][32 + lk8]); \
        __builtin_amdgcn_s_setprio(1);                                          \
        f32x4 p0 = MFMA(wh[0][0], axh, biasv[0]);                               \
        f32x4 pl = MFMA(wl[0][0], axh, z4);                                     \
        f32x4 q0 = MFMA(wh[1][0], axh, biasv[1]);                               \
        f32x4 ql = MFMA(wl[1][0], axh, z4);                                     \
        p0 = MFMA(wh[0][1], uh1, p0);                                           \
        pl = MFMA(wh[0][0], axl, pl);                                           \
        q0 = MFMA(wh[1][1], uh1, q0);                                           \
        ql = MFMA(wh[1][0], axl, ql);                                           \
        p0 = MFMA(wh[0][2], uh2, p0);                                           \
        pl = MFMA(wl[0][1], uh1, pl);                                           \
        q0 = MFMA(wh[1][2], uh2, q0);                                           \
        ql = MFMA(wl[1][1], uh1, ql);                                           \
        pl = MFMA(wh[0][1], ul1, pl);                                           \
        ql = MFMA(wh[1][1], ul1, ql);                                           \
        pl = MFMA(wl[0][2], uh2, pl);                                           \
        ql = MFMA(wl[1][2], uh2, ql);                                           \
        pl = MFMA(wh[0][2], ul2, pl);                                           \
        ql = MFMA(wh[1][2], ul2, ql);                                           \
        __builtin_amdgcn_s_setprio(0);                                          \
        {                                                                       \
            float gi = p0[0] + pl[0], gj = p0[1] + pl[1];                       \
            float gf = p0[2] + pl[2], go = p0[3] + pl[3];                       \
            float ig = sig2(gi), jg = tanh2(gj);                                \
            float fg = sig2(gf), og = sig2(go);                                 \
            cst0 = cst0 * fg + ig * jg;                                         \
            float h = tanh2(cst0 * (2.0f * LOG2E)) * og;                        \
            const int u = 4 * mt0 + kg;                                         \
            unsigned uhb = __float_as_uint(h);                                  \
            Hhi[NXT][lm][u] = (short)(uhb >> 16);                               \
            float hl = h - __uint_as_float(uhb & 0xFFFF0000u);                  \
            Hlo[NXT][lm][u] = (short)(__float_as_uint(hl) >> 16);               \
        }                                                                       \
        if (t1ok) {                                                             \
            float gi = q0[0] + ql[0], gj = q0[1] + ql[1];                       \
            float gf = q0[2] + ql[2], go = q0[3] + ql[3];                       \
            float ig = sig2(gi), jg = tanh2(gj);                                \
            float fg = sig2(gf), og = sig2(go);                                 \
            cst1 = cst1 * fg + ig * jg;                                         \
            float h = tanh2(cst1 * (2.0f * LOG2E)) * og;                        \
            const int u = 4 * mt1 + kg;                                         \
            unsigned uhb = __float_as_uint(h);                                  \
            Hhi[NXT][lm][u] = (short)(uhb >> 16);                               \
            float hl = h - __uint_as_float(uhb & 0xFFFF0000u);                  \
            Hlo[NXT][lm][u] = (short)(__float_as_uint(hl) >> 16);               \
        }                                                                       \
        CVT(nva, nvb, axh, axl)                                                 \
        __syncthreads();                                                        \
    }

    for (int t = 0; t < T_STEPS; t += 2) {
        STEP(0, 1, t)
        STEP(1, 0, t + 1)
    }

    // ---------------- epilogue: out[b] = h . dense_w + dense_b --------------
    // After an even number of steps the live buffer is 0.
    if (tid < BC) {
        float acc = dense_b[0];
        #pragma unroll 4
        for (int uu = 0; uu < H_DIM; ++uu) {
            float h = bf16tof((unsigned short)Hhi[0][tid][uu])
                    + bf16tof((unsigned short)Hlo[0][tid][uu]);
            acc = fmaf(h, dense_w[uu], acc);
        }
        out[b0 + tid] = acc;
    }
}

extern "C" void kernel_launch(void* const* d_in, const int* in_sizes, int n_in,
                              void* d_out, int out_size, void* d_ws, size_t ws_size,
                              hipStream_t stream) {
    const float* x       = (const float*)d_in[0];
    const float* wk      = (const float*)d_in[1];
    const float* bias    = (const float*)d_in[2];
    const float* dense_w = (const float*)d_in[3];
    const float* dense_b = (const float*)d_in[4];
    float* out = (float*)d_out;

    lstm_mfma_kernel<<<B_TOTAL / BC, 512, 0, stream>>>(
        x, wk, bias, dense_w, dense_b, out);
}

// Round 10
// 332.777 us; speedup vs baseline: 2.3548x; 1.1063x over previous
//
#include <hip/hip_runtime.h>

typedef short short8  __attribute__((ext_vector_type(8)));
typedef float f32x4   __attribute__((ext_vector_type(4)));

#define B_TOTAL 4096
#define T_STEPS 512
#define F_IN    32
#define H_DIM   60
#define KW      92      // F + H
#define BC      16      // batch rows per block
#define HPITCH  72      // h-LDS row pitch in halves (144B rows, 2-way-free)

#define MFMA(A, B, C) __builtin_amdgcn_mfma_f32_16x16x32_bf16((A), (B), (C), 0, 0, 0)

__device__ __forceinline__ unsigned short bf16rne(float f) {
    unsigned int u = __float_as_uint(f);
    u += 0x7FFFu + ((u >> 16) & 1u);
    return (unsigned short)(u >> 16);
}
__device__ __forceinline__ float bf16tof(unsigned short s) {
    return __uint_as_float(((unsigned int)s) << 16);
}
__device__ __forceinline__ float rcpf(float z) {
    return __builtin_amdgcn_rcpf(z);            // v_rcp_f32, 1 ulp
}
__device__ __forceinline__ float exp2f_(float z) {
#if __has_builtin(__builtin_amdgcn_exp2f)
    return __builtin_amdgcn_exp2f(z);           // v_exp_f32
#else
    float r; asm("v_exp_f32 %0, %1" : "=v"(r) : "v"(z)); return r;
#endif
}
// zs pre-scaled by log2e:
__device__ __forceinline__ float sig2(float zs) {      // sigmoid(z), zs=z*log2e
    return rcpf(1.0f + exp2f_(-zs));
}
// zs pre-scaled by 2*log2e:
__device__ __forceinline__ float tanh2(float zs) {     // tanh(z), zs=2z*log2e
    return fmaf(-2.0f, rcpf(1.0f + exp2f_(zs)), 1.0f);
}

// float4 pair -> packed bf16 short8 fragment, RNE, via v_cvt_pk_bf16_f32
#define CVTH(VA, VB, OH)                                                        \
    {                                                                           \
        int4 hp;                                                                \
        asm("v_cvt_pk_bf16_f32 %0, %1, %2" : "=v"(hp.x) : "v"((VA).x), "v"((VA).y)); \
        asm("v_cvt_pk_bf16_f32 %0, %1, %2" : "=v"(hp.y) : "v"((VA).z), "v"((VA).w)); \
        asm("v_cvt_pk_bf16_f32 %0, %1, %2" : "=v"(hp.z) : "v"((VB).x), "v"((VB).y)); \
        asm("v_cvt_pk_bf16_f32 %0, %1, %2" : "=v"(hp.w) : "v"((VB).z), "v"((VB).w)); \
        OH = __builtin_bit_cast(short8, hp);                                    \
    }

__global__ __launch_bounds__(512, 2)
void lstm_mfma_kernel(const float* __restrict__ x,
                      const float* __restrict__ wk,
                      const float* __restrict__ bias,
                      const float* __restrict__ dense_w,
                      const float* __restrict__ dense_b,
                      float* __restrict__ out)
{
    // Double-buffered h-state, bf16 hi plane only (weights carry the lo plane).
    __shared__ __align__(16) short Hhi[2][BC][HPITCH];
    __shared__ float Hf[BC][64];            // final-step h, f32, for epilogue

    const int tid  = threadIdx.x;
    const int lane = tid & 63;
    const int w    = tid >> 6;              // wave 0..7
    const int b0   = blockIdx.x * BC;
    const int lm   = lane & 15;
    const int kg   = lane >> 4;             // K octet group 0..3
    const int lk8  = kg * 8;

    const float LOG2E = 1.44269504088896340736f;

    // ---------------- A fragments = W^T (static), exp2-prescaled, hi+lo -----
    // Wave w owns M-tiles 2w, 2w+1. D-layout: lane (lm,kg) acc regs r=0..3
    // hold gates i,j,f,o (pre-scaled) of unit u=4*mt+kg for batch row b=lm.
    // Gate j scaled by 2*log2e (tanh), others log2e (sigmoid); forget +1 folded.
    short8 wh[2][3], wl[2][3];
    f32x4  biasv[2];
    #pragma unroll
    for (int tt = 0; tt < 2; ++tt) {
        const int mt = 2 * w + tt;
        if (mt < 15) {
            const int uo = 4 * mt + kg;
            f32x4 bv;
            #pragma unroll
            for (int r = 0; r < 4; ++r) {
                const float sc = (r == 1) ? 2.0f * LOG2E : LOG2E;
                bv[r] = (bias[r * 60 + uo] + (r == 2 ? 1.0f : 0.0f)) * sc;
            }
            biasv[tt] = bv;
            const int c = 16 * mt + lm;          // A-operand M-row
            const int u = c >> 2, g = c & 3;
            const float gsc = (g == 1) ? 2.0f * LOG2E : LOG2E;
            #pragma unroll
            for (int s = 0; s < 3; ++s) {
                short8 hv, lv;
                #pragma unroll
                for (int e = 0; e < 8; ++e) {
                    const int k = s * 32 + lk8 + e;
                    float wv = (k < KW) ? wk[k * 240 + g * 60 + u] * gsc : 0.0f;
                    unsigned short hh = bf16rne(wv);
                    hv[e] = (short)hh;
                    lv[e] = (short)bf16rne(wv - bf16tof(hh));
                }
                wh[tt][s] = hv;
                wl[tt][s] = lv;
            }
        } else {
            biasv[tt] = (f32x4){0.f, 0.f, 0.f, 0.f};
            #pragma unroll
            for (int s = 0; s < 3; ++s) { wh[tt][s] = (short8)0; wl[tt][s] = (short8)0; }
        }
    }

    // ---------------- zero h buffers (h0 = 0, pad cols 60..63 = 0) ----------
    for (int i = tid; i < 2 * BC * HPITCH; i += 512)
        (&Hhi[0][0][0])[i] = 0;

    // ---------------- x fragment source: lane owns (row lm, k lk8..lk8+7) ---
    const float* xrow = x + (size_t)(b0 + lm) * (T_STEPS * F_IN) + lk8;
    float4 va0 = *reinterpret_cast<const float4*>(xrow);
    float4 vb0 = *reinterpret_cast<const float4*>(xrow + 4);
    short8 axh;
    CVTH(va0, vb0, axh)

    float cst0 = 0.f, cst1 = 0.f;           // cell state for (b=lm, u=4mt+kg)
    const int mt0 = 2 * w, mt1 = 2 * w + 1;
    const bool t1ok = (mt1 < 15);
    __syncthreads();

// one LSTM step: x-frag from regs, h-frag (hi) from LDS[CUR], h -> LDS[NXT]
#define STEP(CUR, NXT, TT)                                                      \
    {                                                                           \
        const int tn = ((TT) + 1 < T_STEPS) ? (TT) + 1 : (TT);                  \
        float4 nva = *reinterpret_cast<const float4*>(xrow + tn * F_IN);        \
        float4 nvb = *reinterpret_cast<const float4*>(xrow + tn * F_IN + 4);    \
        short8 uh1 = *reinterpret_cast<const short8*>(&Hhi[CUR][lm][lk8]);      \
        short8 uh2 = *reinterpret_cast<const short8*>(&Hhi[CUR][lm][32 + lk8]); \
        __builtin_amdgcn_s_setprio(1);                                          \
        f32x4 p = MFMA(wh[0][0], axh, biasv[0]);                                \
        f32x4 q = MFMA(wh[1][0], axh, biasv[1]);                                \
        p = MFMA(wl[0][0], axh, p);                                             \
        q = MFMA(wl[1][0], axh, q);                                             \
        p = MFMA(wh[0][1], uh1, p);                                             \
        q = MFMA(wh[1][1], uh1, q);                                             \
        p = MFMA(wl[0][1], uh1, p);                                             \
        q = MFMA(wl[1][1], uh1, q);                                             \
        p = MFMA(wh[0][2], uh2, p);                                             \
        q = MFMA(wh[1][2], uh2, q);                                             \
        p = MFMA(wl[0][2], uh2, p);                                             \
        q = MFMA(wl[1][2], uh2, q);                                             \
        __builtin_amdgcn_s_setprio(0);                                          \
        {                                                                       \
            float ig = sig2(p[0]), jg = tanh2(p[1]);                            \
            float fg = sig2(p[2]), og = sig2(p[3]);                             \
            cst0 = cst0 * fg + ig * jg;                                         \
            float h = tanh2(cst0 * (2.0f * LOG2E)) * og;                        \
            const int u = 4 * mt0 + kg;                                         \
            Hhi[NXT][lm][u] = (short)bf16rne(h);                                \
            if ((TT) == T_STEPS - 1) Hf[lm][u] = h;                             \
        }                                                                       \
        if (t1ok) {                                                             \
            float ig = sig2(q[0]), jg = tanh2(q[1]);                            \
            float fg = sig2(q[2]), og = sig2(q[3]);                             \
            cst1 = cst1 * fg + ig * jg;                                         \
            float h = tanh2(cst1 * (2.0f * LOG2E)) * og;                        \
            const int u = 4 * mt1 + kg;                                         \
            Hhi[NXT][lm][u] = (short)bf16rne(h);                                \
            if ((TT) == T_STEPS - 1) Hf[lm][u] = h;                             \
        }                                                                       \
        CVTH(nva, nvb, axh)                                                     \
        __syncthreads();                                                        \
    }

    for (int t = 0; t < T_STEPS; t += 2) {
        STEP(0, 1, t)
        STEP(1, 0, t + 1)
    }

    // ---------------- epilogue: out[b] = h . dense_w + dense_b --------------
    if (tid < BC) {
        float acc = dense_b[0];
        #pragma unroll 4
        for (int uu = 0; uu < H_DIM; ++uu)
            acc = fmaf(Hf[tid][uu], dense_w[uu], acc);
        out[b0 + tid] = acc;
    }
}

extern "C" void kernel_launch(void* const* d_in, const int* in_sizes, int n_in,
                              void* d_out, int out_size, void* d_ws, size_t ws_size,
                              hipStream_t stream) {
    const float* x       = (const float*)d_in[0];
    const float* wk      = (const float*)d_in[1];
    const float* bias    = (const float*)d_in[2];
    const float* dense_w = (const float*)d_in[3];
    const float* dense_b = (const float*)d_in[4];
    float* out = (float*)d_out;

    lstm_mfma_kernel<<<B_TOTAL / BC, 512, 0, stream>>>(
        x, wk, bias, dense_w, dense_b, out);
}